// Round 2
// baseline (40162.134 us; speedup 1.0000x reference)
//
#include <hip/hip_runtime.h>
#include <hip/hip_bf16.h>

typedef unsigned short u16;
typedef short s8v __attribute__((ext_vector_type(8)));   // 8 bf16 as shorts (4 VGPRs)
typedef float f4v __attribute__((ext_vector_type(4)));   // MFMA f32 accum

#define NB 64
#define NT 1024
#define ND 512
#define NH 1024

// ---- workspace layout (bytes) ----
// [0,512): grid-barrier state (head0 @ +0, head1 @ +128; {count,gen} uints)
// [512, 512+512KB): h bf16 double buffer [p][head][B][H]
// [1MB, 1MB+64MB): OPTIONAL packed bf16 x [B][T][D]
static const size_t OFF_BAR  = 0;
static const size_t OFF_HB   = 512;
static const size_t SZ_HB    = (size_t)2*2*NB*NH*2;      // 512 KiB
static const size_t OFF_XBF  = (size_t)1<<20;
static const size_t SZ_XBF   = (size_t)NB*NT*ND*2;       // 64 MiB
static const size_t WS_FLOOR = OFF_HB + SZ_HB;           // ~513 KB hard requirement
static const size_t WS_FULL  = OFF_XBF + SZ_XBF;         // ~65 MB fast path

__device__ __forceinline__ u16 f2bf(float f) {           // RNE float->bf16
  union { float f; unsigned u; } v; v.f = f;
  unsigned r = v.u + 0x7fffu + ((v.u >> 16) & 1u);
  return (u16)(r >> 16);
}

// ---- prep: x fp32 -> bf16, same [B][T][D] layout ----
__global__ void pack_x_kernel(const float* __restrict__ x, u16* __restrict__ xb) {
  long long i = (long long)blockIdx.x * 256 + threadIdx.x;  // one 8-elem chunk/thread
  const float4* xp = (const float4*)x;
  float4 a = xp[2*i], b = xp[2*i+1];
  s8v v;
  v[0]=(short)f2bf(a.x); v[1]=(short)f2bf(a.y); v[2]=(short)f2bf(a.z); v[3]=(short)f2bf(a.w);
  v[4]=(short)f2bf(b.x); v[5]=(short)f2bf(b.y); v[6]=(short)f2bf(b.z); v[7]=(short)f2bf(b.w);
  *((s8v*)xb + i) = v;
}

// ---- manual grid barrier (agent scope; works across XCDs, graph-capture safe) ----
__device__ __forceinline__ void gridbar(unsigned* cnt, unsigned* gen, unsigned nb) {
  __syncthreads();
  if (threadIdx.x == 0) {
    __threadfence();                                      // release this block's h stores
    unsigned g = __hip_atomic_load(gen, __ATOMIC_RELAXED, __HIP_MEMORY_SCOPE_AGENT);
    unsigned a = __hip_atomic_fetch_add(cnt, 1u, __ATOMIC_ACQ_REL, __HIP_MEMORY_SCOPE_AGENT);
    if (a == nb - 1u) {
      __hip_atomic_store(cnt, 0u, __ATOMIC_RELAXED, __HIP_MEMORY_SCOPE_AGENT);
      __hip_atomic_fetch_add(gen, 1u, __ATOMIC_RELEASE, __HIP_MEMORY_SCOPE_AGENT);
    } else {
      while (__hip_atomic_load(gen, __ATOMIC_ACQUIRE, __HIP_MEMORY_SCOPE_AGENT) == g)
        __builtin_amdgcn_s_sleep(2);
    }
    __threadfence();                                      // acquire: invalidate L1/L2
  }
  __syncthreads();
}

// ---- persistent GRU ----
// 128 WGs (wg: head=wg>>6, 16-col tile j0=(wg&63)*16), 192 thr = 3 waves (wave g = gate g).
// Weights converted fp32->bf16 into registers at init (48 s8v frags = 192 VGPRs/lane).
// Per step: Cx = x_t@Wslice (K=512), Ch = h@Uslice (K=1024), 16x16x32 bf16 MFMA.
// Waves 0,1 publish z,r via LDS; wave 2 keeps fp32 master h, writes bf16 h + final out.
// One per-head grid barrier per timestep. XBF=1: x pre-packed bf16; XBF=0: convert on the fly.
template<int XBF>
__global__ void __launch_bounds__(192, 1)
rnn_persist(const float* __restrict__ xf, const u16* __restrict__ xb,
            const float* __restrict__ W0, const float* __restrict__ U0,
            const float* __restrict__ W1, const float* __restrict__ U1,
            const float* __restrict__ bi0, const float* __restrict__ br0,
            const float* __restrict__ bi1, const float* __restrict__ br1,
            u16* __restrict__ hb, unsigned* __restrict__ bar,
            float* __restrict__ out) {
  __shared__ float zr[2][64][16];
  const int tid  = threadIdx.x;
  const int lane = tid & 63;
  const int g    = tid >> 6;            // wave id == gate id (z,r,h)
  const int wg   = blockIdx.x;
  const int hd   = wg >> 6;
  const int j0   = (wg & 63) * 16;
  const int cidx = lane & 15;           // A-row-in-tile / B-col / C-col
  const int hi8  = (lane >> 4) << 3;    // k sub-offset for A/B frags
  const int q4   = (lane >> 4) << 2;    // C row group

  const float* W = hd ? W1 : W0;
  const float* U = hd ? U1 : U0;
  const int col = g*1024 + j0 + cidx;   // column in [3H] space for this lane's B-frag

  // one-time: gather W,U slices fp32 -> bf16 register fragments
  // B-frag (16x16x32): lane l holds col=l&15, k = kk*32 + (l>>4)*8 + j
  s8v wf[16], uf[32];
  #pragma unroll
  for (int kk=0;kk<16;++kk) { s8v v;
    #pragma unroll
    for (int j=0;j<8;++j) v[j] = (short)f2bf(W[(size_t)(kk*32 + hi8 + j)*3072 + col]);
    wf[kk]=v; }
  #pragma unroll
  for (int kk=0;kk<32;++kk) { s8v v;
    #pragma unroll
    for (int j=0;j<8;++j) v[j] = (short)f2bf(U[(size_t)(kk*32 + hi8 + j)*3072 + col]);
    uf[kk]=v; }

  const float bis = (hd ? bi1 : bi0)[col];
  const float brs = (hd ? br1 : br0)[col];

  f4v hm[4];                            // wave2: fp32 master h for this 64x16 slice
  #pragma unroll
  for (int m=0;m<4;++m) hm[m] = f4v{0.f,0.f,0.f,0.f};

  unsigned* cnt = bar + hd*32;          // per-head barrier (64 blocks each)
  unsigned* gen = cnt + 1;

  for (int t = 0; t < NT; ++t) {
    const int p = t & 1;
    f4v cx[4], ch[4];
    #pragma unroll
    for (int m=0;m<4;++m){ cx[m]=f4v{0.f,0.f,0.f,0.f}; ch[m]=f4v{0.f,0.f,0.f,0.f}; }

    // Cx += x_t @ Wslice   (K = 512). A-frag: row = m*16+cidx (batch), k = kk*32+hi8+j
    #pragma unroll
    for (int kk=0;kk<16;++kk) {
      #pragma unroll
      for (int m=0;m<4;++m) {
        s8v a;
        if (XBF) {
          a = *(const s8v*)(xb + ((size_t)((m*16+cidx)*NT + t))*ND + hi8 + kk*32);
        } else {
          const float* p4 = xf + ((size_t)((m*16+cidx)*NT + t))*ND + hi8 + kk*32;
          float4 u0 = *(const float4*)p4, u1 = *(const float4*)(p4+4);
          a[0]=(short)f2bf(u0.x); a[1]=(short)f2bf(u0.y); a[2]=(short)f2bf(u0.z); a[3]=(short)f2bf(u0.w);
          a[4]=(short)f2bf(u1.x); a[5]=(short)f2bf(u1.y); a[6]=(short)f2bf(u1.z); a[7]=(short)f2bf(u1.w);
        }
        cx[m] = __builtin_amdgcn_mfma_f32_16x16x32_bf16(a, wf[kk], cx[m], 0,0,0);
      }
    }
    // Ch += h @ Uslice   (K = 1024)
    const u16* hptr0 = hb + (size_t)(p*2 + hd) * (NB*NH) + (size_t)cidx*NH + hi8;
    #pragma unroll
    for (int kk=0;kk<32;++kk) {
      #pragma unroll
      for (int m=0;m<4;++m) {
        s8v a = *(const s8v*)(hptr0 + (size_t)m*16*NH + kk*32);
        ch[m] = __builtin_amdgcn_mfma_f32_16x16x32_bf16(a, uf[kk], ch[m], 0,0,0);
      }
    }

    // gate math. C/D layout: col = cidx, row = m*16 + q4 + q   [m89]
    if (g < 2) {
      #pragma unroll
      for (int m=0;m<4;++m) {
        #pragma unroll
        for (int q=0;q<4;++q) {
          float v = cx[m][q] + ch[m][q] + bis + brs;
          zr[g][m*16 + q4 + q][cidx] = 1.f/(1.f + __expf(-v));
        }
      }
    }
    __syncthreads();
    if (g == 2) {
      u16* hdst = hb + (size_t)((p^1)*2 + hd) * (NB*NH);
      #pragma unroll
      for (int m=0;m<4;++m) {
        #pragma unroll
        for (int q=0;q<4;++q) {
          int row = m*16 + q4 + q;
          float z  = zr[0][row][cidx];
          float r  = zr[1][row][cidx];
          float hc = tanhf(cx[m][q] + bis + r*(ch[m][q] + brs));  // reset_after
          float hn = z*hm[m][q] + (1.f - z)*hc;
          hm[m][q] = hn;
          hdst[(size_t)row*NH + j0 + cidx] = f2bf(hn);
          if (t == NT-1) out[(size_t)hd*(NB*NH) + (size_t)row*NH + j0 + cidx] = hn;
        }
      }
    }
    gridbar(cnt, gen, 64u);
  }
}

extern "C" void kernel_launch(void* const* d_in, const int* in_sizes, int n_in,
                              void* d_out, int out_size, void* d_ws, size_t ws_size,
                              hipStream_t stream) {
  const float* x   = (const float*)d_in[0];
  const float* W0  = (const float*)d_in[1];
  const float* U0  = (const float*)d_in[2];
  const float* bi0 = (const float*)d_in[3];
  const float* br0 = (const float*)d_in[4];
  const float* W1  = (const float*)d_in[5];
  const float* U1  = (const float*)d_in[6];
  const float* bi1 = (const float*)d_in[7];
  const float* br1 = (const float*)d_in[8];
  float* out = (float*)d_out;
  char* ws = (char*)d_ws;

  if (ws_size < WS_FLOOR) {            // cannot run safely at all
    hipMemsetAsync(d_out, 0, (size_t)out_size*4, stream);
    return;
  }

  unsigned* bar = (unsigned*)(ws + OFF_BAR);
  u16* hbb = (u16*)(ws + OFF_HB);
  u16* xbf = (u16*)(ws + OFF_XBF);

  // zero barrier state + h0 (ws is re-poisoned 0xAA before every timed call)
  hipMemsetAsync(ws, 0, OFF_HB + SZ_HB, stream);

  if (ws_size >= WS_FULL) {
    pack_x_kernel<<<dim3((NB*NT*ND/8)/256), dim3(256), 0, stream>>>(x, xbf);
    rnn_persist<1><<<dim3(128), dim3(192), 0, stream>>>(
        nullptr, xbf, W0,U0,W1,U1, bi0,br0,bi1,br1, hbb, bar, out);
  } else {
    rnn_persist<0><<<dim3(128), dim3(192), 0, stream>>>(
        x, nullptr, W0,U0,W1,U1, bi0,br0,bi1,br1, hbb, bar, out);
  }
}